// Round 2
// baseline (114.927 us; speedup 1.0000x reference)
//
#include <hip/hip_runtime.h>
#include <math.h>

#define GRIDN 128
#define NSAMP 192

__global__ __launch_bounds__(NSAMP, 4) void plenoxel_render_kernel(
    const float* __restrict__ vox_grid,   // [128][128][128][28]
    const float* __restrict__ origins,    // [R][3]
    const float* __restrict__ dirs_in,    // [R][3]
    float* __restrict__ out)              // [R][3]
{
    const int ray  = blockIdx.x;
    const int tid  = threadIdx.x;          // sample index 0..191
    const int lane = tid & 63;
    const int wave = tid >> 6;             // 0..2

    // ---- per-ray setup ----
    const float ox = origins[ray * 3 + 0];
    const float oy = origins[ray * 3 + 1];
    const float oz = origins[ray * 3 + 2];
    float dx = dirs_in[ray * 3 + 0];
    float dy = dirs_in[ray * 3 + 1];
    float dz = dirs_in[ray * 3 + 2];
    const float rnrm = 1.0f / sqrtf(dx * dx + dy * dy + dz * dz);
    dx *= rnrm; dy *= rnrm; dz *= rnrm;

    // ---- sample position ----
    const float t  = (float)tid;   // T_NEAR=0, STEP=1
    const float px = fmaf(dx, t, ox);
    const float py = fmaf(dy, t, oy);
    const float pz = fmaf(dz, t, oz);
    const float fx = floorf(px), fy = floorf(py), fz = floorf(pz);
    const int   ix = (int)fx, iy = (int)fy, iz = (int)fz;
    const float rx = px - fx, ry = py - fy, rz = pz - fz;

    // ---- precompute 8 corner offsets (clamped) + validity-zeroed weights ----
    unsigned off[8];
    float    wgt[8];
    {
        int k = 0;
        #pragma unroll
        for (int cx = 0; cx < 2; ++cx)
        #pragma unroll
        for (int cy = 0; cy < 2; ++cy)
        #pragma unroll
        for (int cz = 0; cz < 2; ++cz) {
            const int X = ix + cx, Y = iy + cy, Z = iz + cz;
            const bool valid = ((unsigned)X < GRIDN) & ((unsigned)Y < GRIDN) & ((unsigned)Z < GRIDN);
            const int Xc = min(max(X, 0), GRIDN - 1);
            const int Yc = min(max(Y, 0), GRIDN - 1);
            const int Zc = min(max(Z, 0), GRIDN - 1);
            off[k] = (unsigned)((((Xc << 7) + Yc) << 7) + Zc) * 112u;  // byte offset
            const float w = (cx ? rx : 1.f - rx) * (cy ? ry : 1.f - ry) * (cz ? rz : 1.f - rz);
            wgt[k] = valid ? w : 0.f;
            ++k;
        }
    }

    // ---- branchless gather: 56 independent dwordx4 loads ----
    float vox[28];
    #pragma unroll
    for (int c = 0; c < 28; ++c) vox[c] = 0.f;

    const char* base = (const char*)vox_grid;
    #pragma unroll
    for (int g = 0; g < 8; ++g) {
        const float4* p = (const float4*)(base + off[g]);
        const float w = wgt[g];
        #pragma unroll
        for (int q = 0; q < 7; ++q) {
            const float4 v = p[q];
            vox[q * 4 + 0] = fmaf(w, v.x, vox[q * 4 + 0]);
            vox[q * 4 + 1] = fmaf(w, v.y, vox[q * 4 + 1]);
            vox[q * 4 + 2] = fmaf(w, v.z, vox[q * 4 + 2]);
            vox[q * 4 + 3] = fmaf(w, v.w, vox[q * 4 + 3]);
        }
    }

    // ---- SH basis (computed AFTER gather to shrink live range) ----
    // unit dir: st*cos(phi)=dx, st*sin(phi)=dy, ct=dz
    float sh[9];
    sh[0] = 0.28209479177387814f;
    sh[1] = 0.4886025119029199f * dy;
    sh[2] = 0.4886025119029199f * dz;
    sh[3] = 0.4886025119029199f * dx;
    sh[4] = 1.0925484305920792f * dx * dy;
    sh[5] = 1.0925484305920792f * dy * dz;
    sh[6] = 0.31539156525252005f * (3.f * dz * dz - 1.f);
    sh[7] = 1.0925484305920792f * dx * dz;
    sh[8] = 0.5462742152960396f * (dx * dx - dy * dy);

    // ---- sigma, color ----
    const float sigma = fmaxf(vox[0], 0.f);
    float cr = 0.f, cg = 0.f, cb = 0.f;
    #pragma unroll
    for (int k = 0; k < 9; ++k) {
        cr = fmaf(vox[1 + k],  sh[k], cr);
        cg = fmaf(vox[10 + k], sh[k], cg);
        cb = fmaf(vox[19 + k], sh[k], cb);
    }
    cr = fminf(fmaxf(cr, 0.f), 1.f);
    cg = fminf(fmaxf(cg, 0.f), 1.f);
    cb = fminf(fmaxf(cb, 0.f), 1.f);

    // ---- exclusive prefix-sum of sigma over the 192 samples ----
    float incl = sigma;
    #pragma unroll
    for (int d = 1; d < 64; d <<= 1) {
        const float v = __shfl_up(incl, d, 64);
        if (lane >= d) incl += v;
    }

    __shared__ float wtot[3];
    __shared__ float redr[3], redg[3], redb[3];
    if (lane == 63) wtot[wave] = incl;
    __syncthreads();

    float off_s = 0.f;
    for (int wv = 0; wv < wave; ++wv) off_s += wtot[wv];   // wave-uniform
    const float excl  = off_s + (incl - sigma);
    const float trans = expf(-excl);
    const float alpha = 1.f - expf(-sigma);
    const float wt    = trans * alpha;

    float r = wt * cr, g = wt * cg, b = wt * cb;
    #pragma unroll
    for (int d = 32; d >= 1; d >>= 1) {
        r += __shfl_xor(r, d, 64);
        g += __shfl_xor(g, d, 64);
        b += __shfl_xor(b, d, 64);
    }
    if (lane == 0) { redr[wave] = r; redg[wave] = g; redb[wave] = b; }
    __syncthreads();

    if (tid == 0) {
        const float tfinal = expf(-(wtot[0] + wtot[1] + wtot[2]));
        out[ray * 3 + 0] = redr[0] + redr[1] + redr[2] + tfinal;
        out[ray * 3 + 1] = redg[0] + redg[1] + redg[2] + tfinal;
        out[ray * 3 + 2] = redb[0] + redb[1] + redb[2] + tfinal;
    }
}

extern "C" void kernel_launch(void* const* d_in, const int* in_sizes, int n_in,
                              void* d_out, int out_size, void* d_ws, size_t ws_size,
                              hipStream_t stream) {
    const float* vox_grid = (const float*)d_in[0];
    const float* origins  = (const float*)d_in[1];
    const float* dirs     = (const float*)d_in[2];
    float*       out      = (float*)d_out;
    const int R = in_sizes[1] / 3;   // 2048 rays
    plenoxel_render_kernel<<<R, NSAMP, 0, stream>>>(vox_grid, origins, dirs, out);
}

// Round 3
// 77.568 us; speedup vs baseline: 1.4816x; 1.4816x over previous
//
#include <hip/hip_runtime.h>
#include <math.h>

#define GRIDN 128
#define NSAMP 192
#define BLOCK 256

__global__ __launch_bounds__(BLOCK) void plenoxel_render_kernel(
    const float* __restrict__ vox_grid,   // [128][128][128][28]
    const float* __restrict__ origins,    // [R][3]
    const float* __restrict__ dirs_in,    // [R][3]
    float* __restrict__ out)              // [R][3]
{
    __shared__ unsigned offs_s[NSAMP][8];   // corner byte offsets
    __shared__ float    wgts_s[NSAMP][8];   // validity-zeroed trilinear weights
    __shared__ float4   vox_s[NSAMP * 7];   // gathered 28 floats per sample
    __shared__ float    wtot[3];
    __shared__ float    redr[3], redg[3], redb[3];

    const int ray  = blockIdx.x;
    const int tid  = threadIdx.x;
    const int lane = tid & 63;
    const int wave = tid >> 6;              // 0..3

    // ---- per-ray setup (uniform per block) ----
    const float ox = origins[ray * 3 + 0];
    const float oy = origins[ray * 3 + 1];
    const float oz = origins[ray * 3 + 2];
    float dx = dirs_in[ray * 3 + 0];
    float dy = dirs_in[ray * 3 + 1];
    float dz = dirs_in[ray * 3 + 2];
    const float rn = 1.0f / sqrtf(dx * dx + dy * dy + dz * dz);
    dx *= rn; dy *= rn; dz *= rn;

    // ---- phase 0: per-sample corner offsets + weights (thread = sample) ----
    if (tid < NSAMP) {
        const float t  = (float)tid;
        const float px = fmaf(dx, t, ox);
        const float py = fmaf(dy, t, oy);
        const float pz = fmaf(dz, t, oz);
        const float fx = floorf(px), fy = floorf(py), fz = floorf(pz);
        const int   ix = (int)fx, iy = (int)fy, iz = (int)fz;
        const float rx = px - fx, ry = py - fy, rz = pz - fz;
        #pragma unroll
        for (int g = 0; g < 8; ++g) {
            const int cx = (g >> 2) & 1, cy = (g >> 1) & 1, cz = g & 1;
            const int X = ix + cx, Y = iy + cy, Z = iz + cz;
            const bool valid = ((unsigned)X < GRIDN) & ((unsigned)Y < GRIDN) & ((unsigned)Z < GRIDN);
            const int Xc = min(max(X, 0), GRIDN - 1);
            const int Yc = min(max(Y, 0), GRIDN - 1);
            const int Zc = min(max(Z, 0), GRIDN - 1);
            offs_s[tid][g] = (unsigned)((((Xc << 7) + Yc) << 7) + Zc) * 112u;
            const float w = (cx ? rx : 1.f - rx) * (cy ? ry : 1.f - ry) * (cz ? rz : 1.f - rz);
            wgts_s[tid][g] = valid ? w : 0.f;
        }
    }
    __syncthreads();

    // ---- phase 1: cooperative gather. wave <-> sample, lane = g*8 + q ----
    // One wave-instruction loads all 8 corners' 112B contiguously: ~18 cache
    // lines per sample instead of 56.
    {
        const int g  = lane >> 3;
        const int q  = lane & 7;
        const int qe = (q == 7) ? 6 : q;      // 8th slot duplicates quad 6 (same lines)
        const char* base = (const char*)vox_grid;
        #pragma unroll 4
        for (int it = 0; it < NSAMP / 4; ++it) {
            const int s = it * 4 + wave;
            const unsigned co = offs_s[s][g];
            const float w = (q == 7) ? 0.f : wgts_s[s][g];
            float4 v = *(const float4*)(base + co + qe * 16);
            v.x *= w; v.y *= w; v.z *= w; v.w *= w;
            #pragma unroll
            for (int m = 8; m < 64; m <<= 1) {
                v.x += __shfl_xor(v.x, m, 64);
                v.y += __shfl_xor(v.y, m, 64);
                v.z += __shfl_xor(v.z, m, 64);
                v.w += __shfl_xor(v.w, m, 64);
            }
            if (lane < 7) vox_s[s * 7 + lane] = v;
        }
    }
    __syncthreads();

    // ---- phases 2/3: per-sample shading + transmittance scan (thread = sample) ----
    float sigma = 0.f, incl = 0.f, cr = 0.f, cg = 0.f, cb = 0.f;
    if (tid < NSAMP) {
        float vox[28];
        #pragma unroll
        for (int q2 = 0; q2 < 7; ++q2) {
            const float4 v = vox_s[tid * 7 + q2];
            vox[q2 * 4 + 0] = v.x; vox[q2 * 4 + 1] = v.y;
            vox[q2 * 4 + 2] = v.z; vox[q2 * 4 + 3] = v.w;
        }

        // SH basis: unit dir => st*cp = dx, st*sp = dy, ct = dz
        float sh[9];
        sh[0] = 0.28209479177387814f;
        sh[1] = 0.4886025119029199f * dy;
        sh[2] = 0.4886025119029199f * dz;
        sh[3] = 0.4886025119029199f * dx;
        sh[4] = 1.0925484305920792f * dx * dy;
        sh[5] = 1.0925484305920792f * dy * dz;
        sh[6] = 0.31539156525252005f * (3.f * dz * dz - 1.f);
        sh[7] = 1.0925484305920792f * dx * dz;
        sh[8] = 0.5462742152960396f * (dx * dx - dy * dy);

        sigma = fmaxf(vox[0], 0.f);
        #pragma unroll
        for (int k = 0; k < 9; ++k) {
            cr = fmaf(vox[1 + k],  sh[k], cr);
            cg = fmaf(vox[10 + k], sh[k], cg);
            cb = fmaf(vox[19 + k], sh[k], cb);
        }
        cr = fminf(fmaxf(cr, 0.f), 1.f);
        cg = fminf(fmaxf(cg, 0.f), 1.f);
        cb = fminf(fmaxf(cb, 0.f), 1.f);

        // inclusive scan of sigma within wave
        incl = sigma;
        #pragma unroll
        for (int d = 1; d < 64; d <<= 1) {
            const float v = __shfl_up(incl, d, 64);
            if (lane >= d) incl += v;
        }
        if (lane == 63) wtot[wave] = incl;
    }
    __syncthreads();

    if (tid < NSAMP) {
        float off = 0.f;
        for (int wv = 0; wv < wave; ++wv) off += wtot[wv];   // wave-uniform
        const float excl  = off + (incl - sigma);
        const float trans = expf(-excl);
        const float alpha = 1.f - expf(-sigma);
        const float wt    = trans * alpha;

        float r = wt * cr, g2 = wt * cg, b = wt * cb;
        #pragma unroll
        for (int d = 32; d >= 1; d >>= 1) {
            r  += __shfl_xor(r,  d, 64);
            g2 += __shfl_xor(g2, d, 64);
            b  += __shfl_xor(b,  d, 64);
        }
        if (lane == 0) { redr[wave] = r; redg[wave] = g2; redb[wave] = b; }
    }
    __syncthreads();

    if (tid == 0) {
        const float tfinal = expf(-(wtot[0] + wtot[1] + wtot[2]));
        out[ray * 3 + 0] = redr[0] + redr[1] + redr[2] + tfinal;
        out[ray * 3 + 1] = redg[0] + redg[1] + redg[2] + tfinal;
        out[ray * 3 + 2] = redb[0] + redb[1] + redb[2] + tfinal;
    }
}

extern "C" void kernel_launch(void* const* d_in, const int* in_sizes, int n_in,
                              void* d_out, int out_size, void* d_ws, size_t ws_size,
                              hipStream_t stream) {
    const float* vox_grid = (const float*)d_in[0];
    const float* origins  = (const float*)d_in[1];
    const float* dirs     = (const float*)d_in[2];
    float*       out      = (float*)d_out;
    const int R = in_sizes[1] / 3;   // 2048 rays
    plenoxel_render_kernel<<<R, BLOCK, 0, stream>>>(vox_grid, origins, dirs, out);
}

// Round 4
// 31.091 us; speedup vs baseline: 3.6965x; 2.4949x over previous
//
#include <hip/hip_runtime.h>
#include <math.h>

#define GRIDN 128
#define NSAMP 192
#define BLOCK 256

__global__ __launch_bounds__(BLOCK) void plenoxel_render_kernel(
    const float* __restrict__ vox_grid,   // [128][128][128][28]
    const float* __restrict__ origins,    // [R][3]
    const float* __restrict__ dirs_in,    // [R][3]
    float* __restrict__ out)              // [R][3]
{
    __shared__ uint2  ow_s[NSAMP][8];      // {byte offset, weight bits} per corner
    __shared__ float4 vox_s[NSAMP * 7];    // reduced 28 floats per sample
    __shared__ float  wtot[3];
    __shared__ float  redr[3], redg[3], redb[3];

    const int ray  = blockIdx.x;
    const int tid  = threadIdx.x;
    const int lane = tid & 63;
    const int wave = tid >> 6;              // 0..3

    // ---- per-ray setup (uniform per block) ----
    const float ox = origins[ray * 3 + 0];
    const float oy = origins[ray * 3 + 1];
    const float oz = origins[ray * 3 + 2];
    float dx = dirs_in[ray * 3 + 0];
    float dy = dirs_in[ray * 3 + 1];
    float dz = dirs_in[ray * 3 + 2];
    const float rn = 1.0f / sqrtf(dx * dx + dy * dy + dz * dz);
    dx *= rn; dy *= rn; dz *= rn;

    // ---- phase 0: per-sample corner offsets + weights (thread = sample) ----
    if (tid < NSAMP) {
        const float t  = (float)tid;
        const float px = fmaf(dx, t, ox);
        const float py = fmaf(dy, t, oy);
        const float pz = fmaf(dz, t, oz);
        const float fx = floorf(px), fy = floorf(py), fz = floorf(pz);
        const int   ix = (int)fx, iy = (int)fy, iz = (int)fz;
        const float rx = px - fx, ry = py - fy, rz = pz - fz;
        #pragma unroll
        for (int g = 0; g < 8; ++g) {
            const int cx = (g >> 2) & 1, cy = (g >> 1) & 1, cz = g & 1;
            const int X = ix + cx, Y = iy + cy, Z = iz + cz;
            const bool valid = ((unsigned)X < GRIDN) & ((unsigned)Y < GRIDN) & ((unsigned)Z < GRIDN);
            const int Xc = min(max(X, 0), GRIDN - 1);
            const int Yc = min(max(Y, 0), GRIDN - 1);
            const int Zc = min(max(Z, 0), GRIDN - 1);
            const unsigned off = (unsigned)((((Xc << 7) + Yc) << 7) + Zc) * 112u;
            const float w = (cx ? rx : 1.f - rx) * (cy ? ry : 1.f - ry) * (cz ? rz : 1.f - rz);
            ow_s[tid][g] = make_uint2(off, __float_as_uint(valid ? w : 0.f));
        }
    }
    __syncthreads();

    // ---- phase 1: coalesced gather, in-register corner reduction ----
    // lane = s_sub(2b)*16 + cz(1b)*8 + q(3b); 4 samples per wave-iteration.
    // Each load instruction covers 4 contiguous 224B z-pair regions (~11 lines).
    {
        const int s_sub = lane >> 4;          // 0..3
        const int cz    = (lane >> 3) & 1;
        const int q     = lane & 7;
        const int qe    = (q == 7) ? 6 : q;   // dup quad 6, weight forced 0
        const char* base = (const char*)vox_grid;

        for (int it = 0; it < NSAMP / 16; ++it) {   // 12 rounds
            const int s = it * 16 + wave * 4 + s_sub;
            float4 acc = make_float4(0.f, 0.f, 0.f, 0.f);
            #pragma unroll
            for (int pair = 0; pair < 4; ++pair) {
                const uint2 ow = ow_s[s][pair * 2 + cz];
                const float w  = (q == 7) ? 0.f : __uint_as_float(ow.y);
                const float4 v = *(const float4*)(base + ow.x + qe * 16);
                acc.x = fmaf(w, v.x, acc.x);
                acc.y = fmaf(w, v.y, acc.y);
                acc.z = fmaf(w, v.z, acc.z);
                acc.w = fmaf(w, v.w, acc.w);
            }
            // fold cz=1 into cz=0 (single xor-8 exchange)
            acc.x += __shfl_xor(acc.x, 8, 64);
            acc.y += __shfl_xor(acc.y, 8, 64);
            acc.z += __shfl_xor(acc.z, 8, 64);
            acc.w += __shfl_xor(acc.w, 8, 64);
            if (cz == 0 && q < 7) vox_s[s * 7 + q] = acc;
        }
    }
    __syncthreads();

    // ---- phases 2/3: per-sample shading + transmittance scan (thread = sample) ----
    float sigma = 0.f, incl = 0.f, cr = 0.f, cg = 0.f, cb = 0.f;
    if (tid < NSAMP) {
        float vox[28];
        #pragma unroll
        for (int q2 = 0; q2 < 7; ++q2) {
            const float4 v = vox_s[tid * 7 + q2];
            vox[q2 * 4 + 0] = v.x; vox[q2 * 4 + 1] = v.y;
            vox[q2 * 4 + 2] = v.z; vox[q2 * 4 + 3] = v.w;
        }

        // SH basis: unit dir => st*cp = dx, st*sp = dy, ct = dz
        float sh[9];
        sh[0] = 0.28209479177387814f;
        sh[1] = 0.4886025119029199f * dy;
        sh[2] = 0.4886025119029199f * dz;
        sh[3] = 0.4886025119029199f * dx;
        sh[4] = 1.0925484305920792f * dx * dy;
        sh[5] = 1.0925484305920792f * dy * dz;
        sh[6] = 0.31539156525252005f * (3.f * dz * dz - 1.f);
        sh[7] = 1.0925484305920792f * dx * dz;
        sh[8] = 0.5462742152960396f * (dx * dx - dy * dy);

        sigma = fmaxf(vox[0], 0.f);
        #pragma unroll
        for (int k = 0; k < 9; ++k) {
            cr = fmaf(vox[1 + k],  sh[k], cr);
            cg = fmaf(vox[10 + k], sh[k], cg);
            cb = fmaf(vox[19 + k], sh[k], cb);
        }
        cr = fminf(fmaxf(cr, 0.f), 1.f);
        cg = fminf(fmaxf(cg, 0.f), 1.f);
        cb = fminf(fmaxf(cb, 0.f), 1.f);

        // inclusive scan of sigma within wave
        incl = sigma;
        #pragma unroll
        for (int d = 1; d < 64; d <<= 1) {
            const float v = __shfl_up(incl, d, 64);
            if (lane >= d) incl += v;
        }
        if (lane == 63) wtot[wave] = incl;
    }
    __syncthreads();

    if (tid < NSAMP) {
        float off = 0.f;
        for (int wv = 0; wv < wave; ++wv) off += wtot[wv];   // wave-uniform
        const float excl  = off + (incl - sigma);
        const float trans = expf(-excl);
        const float alpha = 1.f - expf(-sigma);
        const float wt    = trans * alpha;

        float r = wt * cr, g2 = wt * cg, b = wt * cb;
        #pragma unroll
        for (int d = 32; d >= 1; d >>= 1) {
            r  += __shfl_xor(r,  d, 64);
            g2 += __shfl_xor(g2, d, 64);
            b  += __shfl_xor(b,  d, 64);
        }
        if (lane == 0) { redr[wave] = r; redg[wave] = g2; redb[wave] = b; }
    }
    __syncthreads();

    if (tid == 0) {
        const float tfinal = expf(-(wtot[0] + wtot[1] + wtot[2]));
        out[ray * 3 + 0] = redr[0] + redr[1] + redr[2] + tfinal;
        out[ray * 3 + 1] = redg[0] + redg[1] + redg[2] + tfinal;
        out[ray * 3 + 2] = redb[0] + redb[1] + redb[2] + tfinal;
    }
}

extern "C" void kernel_launch(void* const* d_in, const int* in_sizes, int n_in,
                              void* d_out, int out_size, void* d_ws, size_t ws_size,
                              hipStream_t stream) {
    const float* vox_grid = (const float*)d_in[0];
    const float* origins  = (const float*)d_in[1];
    const float* dirs     = (const float*)d_in[2];
    float*       out      = (float*)d_out;
    const int R = in_sizes[1] / 3;   // 2048 rays
    plenoxel_render_kernel<<<R, BLOCK, 0, stream>>>(vox_grid, origins, dirs, out);
}